// Round 6
// baseline (179.383 us; speedup 1.0000x reference)
//
#include <hip/hip_runtime.h>
#include <stdint.h>

typedef __attribute__((ext_vector_type(8))) short short8;
typedef __attribute__((ext_vector_type(4))) float floatx4;
typedef __attribute__((ext_vector_type(16))) float floatx16;

#define DEV static __device__ __forceinline__

DEV unsigned short f2bf(float f) {
  union { float f; uint32_t u; } v; v.f = f;
  return (unsigned short)((v.u + 0x7FFFu + ((v.u >> 16) & 1u)) >> 16);
}
DEV float bf2f(unsigned short h) {
  union { uint32_t u; float f; } v; v.u = ((uint32_t)h) << 16;
  return v.f;
}
DEV uint32_t cvtpk(float lo, float hi) {
  uint32_t d;
  asm("v_cvt_pk_bf16_f32 %0, %1, %2" : "=v"(d) : "v"(lo), "v"(hi));
  return d;
}
DEV void gload_lds16(const void* g, void* l) {
  __builtin_amdgcn_global_load_lds(
      (const __attribute__((address_space(1))) uint32_t*)g,
      (__attribute__((address_space(3))) uint32_t*)l, 16, 0, 0);
}

// ---------- fp32 -> bf16 convert: [X 4M][wq 1M][wk 1M][wv 1M][wo 1M] ----------
__global__ __launch_bounds__(256) void k_convert(
    const float* __restrict__ X, const float* __restrict__ Wq,
    const float* __restrict__ Wk, const float* __restrict__ Wv,
    const float* __restrict__ Wo, unsigned short* __restrict__ out) {
  long gid = (long)blockIdx.x * 256 + threadIdx.x;
  long e = gid * 8;
  int seg = (int)(e >> 20);
  const float* src; long base;
  if (seg < 4)      { src = X;  base = 0; }
  else if (seg == 4){ src = Wq; base = 4l << 20; }
  else if (seg == 5){ src = Wk; base = 5l << 20; }
  else if (seg == 6){ src = Wv; base = 6l << 20; }
  else              { src = Wo; base = 7l << 20; }
  const float4* s4 = (const float4*)(src + (e - base));
  float4 a = s4[0], b = s4[1];
  union { uint4 q; unsigned short s[8]; } u;
  u.s[0] = f2bf(a.x); u.s[1] = f2bf(a.y); u.s[2] = f2bf(a.z); u.s[3] = f2bf(a.w);
  u.s[4] = f2bf(b.x); u.s[5] = f2bf(b.y); u.s[6] = f2bf(b.z); u.s[7] = f2bf(b.w);
  *(uint4*)(out + e) = u.q;
}

// ---------- GEMM C = A * W^T   (A: MxK bf16 rm, W: NxK bf16 rm) ----------
template <int MODE>
__global__ __launch_bounds__(256) void k_gemm(
    const unsigned short* __restrict__ A,
    const unsigned short* __restrict__ B0, const unsigned short* __restrict__ B1,
    const unsigned short* __restrict__ B2,
    unsigned short* __restrict__ Cq, unsigned short* __restrict__ Ck,
    unsigned short* __restrict__ Cv, float* __restrict__ Cf, int K) {
  __shared__ unsigned short At[128 * 64];
  __shared__ unsigned short Bt[128 * 64];
  const int tid = threadIdx.x, lane = tid & 63, wid = tid >> 6;
  const int wm = (wid >> 1) * 64, wn = (wid & 1) * 64;
  const int g = lane >> 4, c0 = lane & 15;
  const int bm0 = blockIdx.x * 128;
  const int bnG = blockIdx.y * 128;
  const unsigned short* Bp;
  int bn0;
  if constexpr (MODE == 0) {
    int wsel = bnG >> 10;
    Bp = wsel == 0 ? B0 : (wsel == 1 ? B1 : B2);
    bn0 = bnG & 1023;
  } else { Bp = B0; bn0 = bnG; }
  floatx4 acc[4][4] = {};
  for (int kt = 0; kt < K; kt += 64) {
#pragma unroll
    for (int i = 0; i < 4; ++i) {
      int o = (wid * 64 + lane) * 16 + i * 4096;
      int row = o >> 7, k0 = (o & 127) >> 1;
      gload_lds16((const char*)A  + ((long)(bm0 + row) * K + kt + k0) * 2, (char*)At + o);
      gload_lds16((const char*)Bp + ((long)(bn0 + row) * K + kt + k0) * 2, (char*)Bt + o);
    }
    __syncthreads();
#pragma unroll
    for (int kk = 0; kk < 2; ++kk) {
      const int kb = kk * 64 + g * 16;
      short8 av[4], bv[4];
#pragma unroll
      for (int mi = 0; mi < 4; ++mi)
        av[mi] = *(const short8*)((const char*)At + (wm + mi * 16 + c0) * 128 + kb);
#pragma unroll
      for (int ni = 0; ni < 4; ++ni)
        bv[ni] = *(const short8*)((const char*)Bt + (wn + ni * 16 + c0) * 128 + kb);
#pragma unroll
      for (int mi = 0; mi < 4; ++mi)
#pragma unroll
        for (int ni = 0; ni < 4; ++ni)
          acc[mi][ni] = __builtin_amdgcn_mfma_f32_16x16x32_bf16(av[mi], bv[ni], acc[mi][ni], 0, 0, 0);
    }
    __syncthreads();
  }
#pragma unroll
  for (int mi = 0; mi < 4; ++mi)
#pragma unroll
    for (int ni = 0; ni < 4; ++ni)
#pragma unroll
      for (int i = 0; i < 4; ++i) {
        int r = bm0 + wm + mi * 16 + 4 * g + i;
        int cg = bnG + wn + ni * 16 + c0;
        float v = acc[mi][ni][i];
        if constexpr (MODE == 0) {
          int wsel = cg >> 10, cc = cg & 1023, h = cc >> 6, dkk = cc & 63;
          int bb = r >> 11, ll = r & 2047;
          unsigned short* dst = wsel == 0 ? Cq : (wsel == 1 ? Ck : Cv);
          dst[((long)(bb * 16 + h) * 2048 + ll) * 64 + dkk] = f2bf(v);
        } else {
          Cf[(long)r * 1024 + cg] = v;
        }
      }
}

// ---------- RoPE in place on Q||K (contiguous, each [2,16,2048,64] bf16) ----------
__global__ __launch_bounds__(256) void k_rope(unsigned short* __restrict__ QK, float qscale) {
  int gid = blockIdx.x * 256 + threadIdx.x;  // 262144 threads: (row, half)
  int row = gid >> 1, hf = gid & 1;          // rows 0..65535 = Q, rest = K
  float scale = row < 65536 ? qscale : 1.0f;
  int l = row & 2047;
  unsigned short* p = QK + (long)row * 64 + hf * 32;
  union { uint4 q[4]; unsigned short s[32]; } u;
#pragma unroll
  for (int i = 0; i < 4; ++i) u.q[i] = ((const uint4*)p)[i];
  float lf = (float)l;
#pragma unroll
  for (int j = 0; j < 16; ++j) {
    int pp = hf * 16 + j;
    float ang = lf * exp2f(-(float)pp * 0.4152410118609203f);  // log2(10000)/32
    float sv, cv; sincosf(ang, &sv, &cv);
    float x1 = bf2f(u.s[2 * j]), x2 = bf2f(u.s[2 * j + 1]);
    u.s[2 * j]     = f2bf((x1 * cv - x2 * sv) * scale);
    u.s[2 * j + 1] = f2bf((x1 * sv + x2 * cv) * scale);
  }
#pragma unroll
  for (int i = 0; i < 4; ++i) ((uint4*)p)[i] = u.q[i];
}

// ---------- V [bh, 2048, 64] -> V^T [bh, 64, 2080] (padded stride vs 4KB alias) ----------
#define VT_STRIDE 2080
__global__ __launch_bounds__(256) void k_transpose(
    const unsigned short* __restrict__ in, unsigned short* __restrict__ out) {
  __shared__ unsigned short t[64][68];
  const int bh = blockIdx.x >> 5, lt = blockIdx.x & 31;
  const int tid = threadIdx.x;
  const unsigned short* src = in + ((long)bh * 2048 + lt * 64) * 64;
#pragma unroll
  for (int p = 0; p < 2; ++p) {
    int idx = tid + p * 256;
    int row = idx >> 3, c = (idx & 7) * 8;
    union { uint4 q; unsigned short s[8]; } u;
    u.q = *(const uint4*)(src + row * 64 + c);
#pragma unroll
    for (int j = 0; j < 8; ++j) t[row][c + j] = u.s[j];
  }
  __syncthreads();
  unsigned short* dst = out + (long)bh * 64 * VT_STRIDE + lt * 64;
#pragma unroll
  for (int p = 0; p < 2; ++p) {
    int idx = tid + p * 256;
    int dv = idx >> 3, lc = (idx & 7) * 8;
    union { uint4 q; unsigned short s[8]; } u;
#pragma unroll
    for (int j = 0; j < 8; ++j) u.s[j] = t[lc + j][dv];
    *(uint4*)(dst + (long)dv * VT_STRIDE + lc) = u.q;
  }
}

// ---------- causal flash attention: 32x32 swapped MFMA + K reg-prefetch ----------
// 1 wave/block, 32 q-rows per wave. Lane (h=lane>>5, c=lane&31) owns q-row q0+c.
// S^T via mfma_32x32x16(A=K,B=Q): reg r -> kv-local (r&3)+8*(r>>2)+4h, col=c.
// K(T+1) fragments load at top of tile T (register double-buffer, static idx).
DEV void attn_tile(int T, int nt, int qabs, int h, int c,
                   const unsigned short* __restrict__ kbase,
                   const unsigned short* __restrict__ vbase,
                   const short8 (&qf)[4],
                   const short8 (&kc0)[4], const short8 (&kc1)[4],
                   short8 (&kn0)[4], short8 (&kn1)[4],
                   floatx16& ctx0, floatx16& ctx1, float& m_, float& l_) {
  // prefetch K(T+1) into the other buffer (clamped on last tile; result unused)
  {
    const int Tn = T + 1 < nt ? T + 1 : T;
    const unsigned short* kpn = kbase + (long)Tn * 4096;
#pragma unroll
    for (int d = 0; d < 4; ++d) kn0[d] = *(const short8*)(kpn + d * 16);
#pragma unroll
    for (int d = 0; d < 4; ++d) kn1[d] = *(const short8*)(kpn + 32 * 64 + d * 16);
  }
  // V^T fragments for this tile (consumed after softmax -> latency hidden)
  const unsigned short* vp = vbase + T * 64;
  short8 vf0[4], vf1[4];
#pragma unroll
  for (int m = 0; m < 4; ++m) vf0[m] = *(const short8*)(vp + m * 16);
#pragma unroll
  for (int m = 0; m < 4; ++m) vf1[m] = *(const short8*)(vp + 32 * VT_STRIDE + m * 16);

  // S^T tiles from current (already-resident) K fragments
  floatx16 s0 = {}, s1 = {};
#pragma unroll
  for (int d = 0; d < 4; ++d)
    s0 = __builtin_amdgcn_mfma_f32_32x32x16_bf16(kc0[d], qf[d], s0, 0, 0, 0);
#pragma unroll
  for (int d = 0; d < 4; ++d)
    s1 = __builtin_amdgcn_mfma_f32_32x32x16_bf16(kc1[d], qf[d], s1, 0, 0, 0);

  // causal mask (uniform branch, last tile only)
  if (T == nt - 1) {
    const int kvb = T * 64 + 4 * h;
#pragma unroll
    for (int r = 0; r < 16; ++r) {
      const int off = (r & 3) + 8 * (r >> 2);
      if (kvb + off > qabs) s0[r] = -1e30f;
      if (kvb + 32 + off > qabs) s1[r] = -1e30f;
    }
  }
  // softmax (scalar per lane): in-lane trees + 2 cross-lane ops
  float mx = s0[0];
#pragma unroll
  for (int r = 1; r < 16; ++r) mx = fmaxf(mx, s0[r]);
#pragma unroll
  for (int r = 0; r < 16; ++r) mx = fmaxf(mx, s1[r]);
  mx = fmaxf(mx, __shfl_xor(mx, 32));
  float mn = fmaxf(m_, mx);
  float sc = exp2f(m_ - mn);
  m_ = mn;
#pragma unroll
  for (int r = 0; r < 16; ++r) s0[r] = exp2f(s0[r] - m_);
#pragma unroll
  for (int r = 0; r < 16; ++r) s1[r] = exp2f(s1[r] - m_);
  float rs = 0.f;
#pragma unroll
  for (int r = 0; r < 16; ++r) rs += s0[r] + s1[r];
  rs += __shfl_xor(rs, 32);
  l_ = l_ * sc + rs;
#pragma unroll
  for (int r = 0; r < 16; ++r) { ctx0[r] *= sc; ctx1[r] *= sc; }

  // pack P to bf16 dwords
  uint32_t pd0[8], pd1[8];
#pragma unroll
  for (int d = 0; d < 8; ++d) {
    pd0[d] = cvtpk(s0[2 * d], s0[2 * d + 1]);
    pd1[d] = cvtpk(s1[2 * d], s1[2 * d + 1]);
  }
  // PV: per kvs-subtile, per kseg: B-frag via 2 shfl_xor(32) + selects
#pragma unroll
  for (int kvs = 0; kvs < 2; ++kvs) {
    const uint32_t* pd = kvs ? pd1 : pd0;
#pragma unroll
    for (int ks = 0; ks < 2; ++ks) {
      uint32_t sel0 = h ? pd[4 * ks]     : pd[4 * ks + 2];
      uint32_t sel1 = h ? pd[4 * ks + 1] : pd[4 * ks + 3];
      uint32_t r0 = __shfl_xor(sel0, 32);
      uint32_t r1 = __shfl_xor(sel1, 32);
      union { uint32_t u[4]; short8 s; } bu;
      bu.u[0] = h ? r0 : pd[4 * ks];
      bu.u[1] = h ? r1 : pd[4 * ks + 1];
      bu.u[2] = h ? pd[4 * ks + 2] : r0;
      bu.u[3] = h ? pd[4 * ks + 3] : r1;
      ctx0 = __builtin_amdgcn_mfma_f32_32x32x16_bf16(vf0[kvs * 2 + ks], bu.s, ctx0, 0, 0, 0);
      ctx1 = __builtin_amdgcn_mfma_f32_32x32x16_bf16(vf1[kvs * 2 + ks], bu.s, ctx1, 0, 0, 0);
    }
  }
}

__global__ __launch_bounds__(64) void k_attn(
    const unsigned short* __restrict__ Q, const unsigned short* __restrict__ K,
    const unsigned short* __restrict__ Vt, unsigned short* __restrict__ O) {
  const int bid = blockIdx.x;              // 2048 blocks = 8 XCD * 256
  const int xcd = bid & 7, idx = bid >> 3;
  const int bh = xcd * 4 + (idx >> 6);     // 4 heads per XCD -> K/V L2-resident
  const int qs = 63 - (idx & 63);          // heavy q-subtiles first
  const int lane = threadIdx.x & 63;
  const int h = lane >> 5, c = lane & 31;
  const long hoff = (long)bh * 2048 * 64;
  const unsigned short* Qh = Q + hoff;
  const unsigned short* Kh = K + hoff;
  const unsigned short* Vh = Vt + (long)bh * 64 * VT_STRIDE;
  const int q0 = qs * 32, qabs = q0 + c;
  const int nt = (qs >> 1) + 1;
  const unsigned short* kbase = Kh + (long)c * 64 + 8 * h;
  const unsigned short* vbase = Vh + (long)c * VT_STRIDE + 8 * h;

  // Q fragment (B-operand), hoisted: qf[dseg] = Q[q0+c][dseg*16+8h+j]
  short8 qf[4];
#pragma unroll
  for (int d = 0; d < 4; ++d)
    qf[d] = *(const short8*)(Qh + (long)(q0 + c) * 64 + d * 16 + 8 * h);

  floatx16 ctx0 = {}, ctx1 = {};  // ctx^T[dv][q]
  float m_ = -1e30f, l_ = 0.f;

  // prologue: K(0) into buffer A
  short8 kA0[4], kA1[4], kB0[4], kB1[4];
#pragma unroll
  for (int d = 0; d < 4; ++d) kA0[d] = *(const short8*)(kbase + d * 16);
#pragma unroll
  for (int d = 0; d < 4; ++d) kA1[d] = *(const short8*)(kbase + 32 * 64 + d * 16);

  int T = 0;
  while (true) {
    attn_tile(T, nt, qabs, h, c, kbase, vbase, qf, kA0, kA1, kB0, kB1, ctx0, ctx1, m_, l_);
    if (++T >= nt) break;
    attn_tile(T, nt, qabs, h, c, kbase, vbase, qf, kB0, kB1, kA0, kA1, ctx0, ctx1, m_, l_);
    if (++T >= nt) break;
  }
  // epilogue: lane owns q-row q0+c; dv = dvs*32 + 8m + 4h + (0..3)
  const int b = bh >> 4, hd = bh & 15;
  float inv = 1.f / l_;
  unsigned short* orow = O + (long)(b * 2048 + q0 + c) * 1024 + hd * 64;
#pragma unroll
  for (int m = 0; m < 4; ++m) {
    uint2 w0, w1;
    w0.x = cvtpk(ctx0[4 * m] * inv, ctx0[4 * m + 1] * inv);
    w0.y = cvtpk(ctx0[4 * m + 2] * inv, ctx0[4 * m + 3] * inv);
    *(uint2*)(orow + 8 * m + 4 * h) = w0;
    w1.x = cvtpk(ctx1[4 * m] * inv, ctx1[4 * m + 1] * inv);
    w1.y = cvtpk(ctx1[4 * m + 2] * inv, ctx1[4 * m + 3] * inv);
    *(uint2*)(orow + 32 + 8 * m + 4 * h) = w1;
  }
}

extern "C" void kernel_launch(void* const* d_in, const int* in_sizes, int n_in,
                              void* d_out, int out_size, void* d_ws, size_t ws_size,
                              hipStream_t stream) {
  const float* X  = (const float*)d_in[0];
  const float* Wq = (const float*)d_in[1];
  const float* Wk = (const float*)d_in[2];
  const float* Wv = (const float*)d_in[3];
  const float* Wo = (const float*)d_in[4];
  unsigned short* Xb  = (unsigned short*)d_ws;   // 4M elems bf16 X
  unsigned short* Wqb = Xb + (4l << 20);
  unsigned short* Wkb = Xb + (5l << 20);
  unsigned short* Wvb = Xb + (6l << 20);
  unsigned short* Wob = Xb + (7l << 20);
  unsigned short* Qw  = Xb + (8l << 20);         // [2,16,2048,64]
  unsigned short* Kw  = Xb + (12l << 20);
  unsigned short* Vw  = Xb + (16l << 20);
  unsigned short* Vtw = Xb;  // V^T [32][64][2080]: aliases X/Wq/Wk/Wv (dead after QKV GEMM)
  unsigned short* Cw  = Xb + (20l << 20);        // ctx [b,l,1024]
  float* Out = (float*)d_out;

  k_convert<<<4096, 256, 0, stream>>>(X, Wq, Wk, Wv, Wo, Xb);
  k_gemm<0><<<dim3(32, 24), 256, 0, stream>>>(Xb, Wqb, Wkb, Wvb, Qw, Kw, Vw, nullptr, 1024);
  k_rope<<<1024, 256, 0, stream>>>(Qw, 0.18033688011112042f);  // log2(e)/8
  k_transpose<<<1024, 256, 0, stream>>>(Vw, Vtw);
  k_attn<<<2048, 64, 0, stream>>>(Qw, Kw, Vtw, Cw);
  k_gemm<1><<<dim3(32, 8), 256, 0, stream>>>(Cw, Wob, nullptr, nullptr,
                                             nullptr, nullptr, nullptr, Out, 1024);
}

// Round 7
// 159.197 us; speedup vs baseline: 1.1268x; 1.1268x over previous
//
#include <hip/hip_runtime.h>
#include <stdint.h>

typedef __attribute__((ext_vector_type(8))) short short8;
typedef __attribute__((ext_vector_type(4))) float floatx4;
typedef __attribute__((ext_vector_type(16))) float floatx16;

#define DEV static __device__ __forceinline__

DEV unsigned short f2bf(float f) {
  union { float f; uint32_t u; } v; v.f = f;
  return (unsigned short)((v.u + 0x7FFFu + ((v.u >> 16) & 1u)) >> 16);
}
DEV float bf2f(unsigned short h) {
  union { uint32_t u; float f; } v; v.u = ((uint32_t)h) << 16;
  return v.f;
}
DEV uint32_t cvtpk(float lo, float hi) {
  uint32_t d;
  asm("v_cvt_pk_bf16_f32 %0, %1, %2" : "=v"(d) : "v"(lo), "v"(hi));
  return d;
}
DEV void gload_lds16(const void* g, void* l) {
  __builtin_amdgcn_global_load_lds(
      (const __attribute__((address_space(1))) uint32_t*)g,
      (__attribute__((address_space(3))) uint32_t*)l, 16, 0, 0);
}

// ---------- fp32 -> bf16 convert: [X 4M][wq 1M][wk 1M][wv 1M][wo 1M] ----------
__global__ __launch_bounds__(256) void k_convert(
    const float* __restrict__ X, const float* __restrict__ Wq,
    const float* __restrict__ Wk, const float* __restrict__ Wv,
    const float* __restrict__ Wo, unsigned short* __restrict__ out) {
  long gid = (long)blockIdx.x * 256 + threadIdx.x;
  long e = gid * 8;
  int seg = (int)(e >> 20);
  const float* src; long base;
  if (seg < 4)      { src = X;  base = 0; }
  else if (seg == 4){ src = Wq; base = 4l << 20; }
  else if (seg == 5){ src = Wk; base = 5l << 20; }
  else if (seg == 6){ src = Wv; base = 6l << 20; }
  else              { src = Wo; base = 7l << 20; }
  const float4* s4 = (const float4*)(src + (e - base));
  float4 a = s4[0], b = s4[1];
  union { uint4 q; unsigned short s[8]; } u;
  u.s[0] = f2bf(a.x); u.s[1] = f2bf(a.y); u.s[2] = f2bf(a.z); u.s[3] = f2bf(a.w);
  u.s[4] = f2bf(b.x); u.s[5] = f2bf(b.y); u.s[6] = f2bf(b.z); u.s[7] = f2bf(b.w);
  *(uint4*)(out + e) = u.q;
}

// ---------- GEMM C = A * W^T   (A: MxK bf16 rm, W: NxK bf16 rm) ----------
template <int MODE>
__global__ __launch_bounds__(256) void k_gemm(
    const unsigned short* __restrict__ A,
    const unsigned short* __restrict__ B0, const unsigned short* __restrict__ B1,
    const unsigned short* __restrict__ B2,
    unsigned short* __restrict__ Cq, unsigned short* __restrict__ Ck,
    unsigned short* __restrict__ Cv, float* __restrict__ Cf, int K) {
  __shared__ unsigned short At[128 * 64];
  __shared__ unsigned short Bt[128 * 64];
  const int tid = threadIdx.x, lane = tid & 63, wid = tid >> 6;
  const int wm = (wid >> 1) * 64, wn = (wid & 1) * 64;
  const int g = lane >> 4, c0 = lane & 15;
  const int bm0 = blockIdx.x * 128;
  const int bnG = blockIdx.y * 128;
  const unsigned short* Bp;
  int bn0;
  if constexpr (MODE == 0) {
    int wsel = bnG >> 10;
    Bp = wsel == 0 ? B0 : (wsel == 1 ? B1 : B2);
    bn0 = bnG & 1023;
  } else { Bp = B0; bn0 = bnG; }
  floatx4 acc[4][4] = {};
  for (int kt = 0; kt < K; kt += 64) {
#pragma unroll
    for (int i = 0; i < 4; ++i) {
      int o = (wid * 64 + lane) * 16 + i * 4096;
      int row = o >> 7, k0 = (o & 127) >> 1;
      gload_lds16((const char*)A  + ((long)(bm0 + row) * K + kt + k0) * 2, (char*)At + o);
      gload_lds16((const char*)Bp + ((long)(bn0 + row) * K + kt + k0) * 2, (char*)Bt + o);
    }
    __syncthreads();
#pragma unroll
    for (int kk = 0; kk < 2; ++kk) {
      const int kb = kk * 64 + g * 16;
      short8 av[4], bv[4];
#pragma unroll
      for (int mi = 0; mi < 4; ++mi)
        av[mi] = *(const short8*)((const char*)At + (wm + mi * 16 + c0) * 128 + kb);
#pragma unroll
      for (int ni = 0; ni < 4; ++ni)
        bv[ni] = *(const short8*)((const char*)Bt + (wn + ni * 16 + c0) * 128 + kb);
#pragma unroll
      for (int mi = 0; mi < 4; ++mi)
#pragma unroll
        for (int ni = 0; ni < 4; ++ni)
          acc[mi][ni] = __builtin_amdgcn_mfma_f32_16x16x32_bf16(av[mi], bv[ni], acc[mi][ni], 0, 0, 0);
    }
    __syncthreads();
  }
#pragma unroll
  for (int mi = 0; mi < 4; ++mi)
#pragma unroll
    for (int ni = 0; ni < 4; ++ni)
#pragma unroll
      for (int i = 0; i < 4; ++i) {
        int r = bm0 + wm + mi * 16 + 4 * g + i;
        int cg = bnG + wn + ni * 16 + c0;
        float v = acc[mi][ni][i];
        if constexpr (MODE == 0) {
          int wsel = cg >> 10, cc = cg & 1023, h = cc >> 6, dkk = cc & 63;
          int bb = r >> 11, ll = r & 2047;
          unsigned short* dst = wsel == 0 ? Cq : (wsel == 1 ? Ck : Cv);
          dst[((long)(bb * 16 + h) * 2048 + ll) * 64 + dkk] = f2bf(v);
        } else {
          Cf[(long)r * 1024 + cg] = v;
        }
      }
}

// ---------- RoPE in place on Q||K (contiguous, each [2,16,2048,64] bf16) ----------
__global__ __launch_bounds__(256) void k_rope(unsigned short* __restrict__ QK, float qscale) {
  int gid = blockIdx.x * 256 + threadIdx.x;  // 262144 threads: (row, half)
  int row = gid >> 1, hf = gid & 1;          // rows 0..65535 = Q, rest = K
  float scale = row < 65536 ? qscale : 1.0f;
  int l = row & 2047;
  unsigned short* p = QK + (long)row * 64 + hf * 32;
  union { uint4 q[4]; unsigned short s[32]; } u;
#pragma unroll
  for (int i = 0; i < 4; ++i) u.q[i] = ((const uint4*)p)[i];
  float lf = (float)l;
#pragma unroll
  for (int j = 0; j < 16; ++j) {
    int pp = hf * 16 + j;
    float ang = lf * exp2f(-(float)pp * 0.4152410118609203f);  // log2(10000)/32
    float sv, cv; sincosf(ang, &sv, &cv);
    float x1 = bf2f(u.s[2 * j]), x2 = bf2f(u.s[2 * j + 1]);
    u.s[2 * j]     = f2bf((x1 * cv - x2 * sv) * scale);
    u.s[2 * j + 1] = f2bf((x1 * sv + x2 * cv) * scale);
  }
#pragma unroll
  for (int i = 0; i < 4; ++i) ((uint4*)p)[i] = u.q[i];
}

// ---------- V [bh, 2048, 64] -> V^T [bh, 64, 2080] (padded stride vs 4KB alias) ----------
#define VT_STRIDE 2080
__global__ __launch_bounds__(256) void k_transpose(
    const unsigned short* __restrict__ in, unsigned short* __restrict__ out) {
  __shared__ unsigned short t[64][68];
  const int bh = blockIdx.x >> 5, lt = blockIdx.x & 31;
  const int tid = threadIdx.x;
  const unsigned short* src = in + ((long)bh * 2048 + lt * 64) * 64;
#pragma unroll
  for (int p = 0; p < 2; ++p) {
    int idx = tid + p * 256;
    int row = idx >> 3, c = (idx & 7) * 8;
    union { uint4 q; unsigned short s[8]; } u;
    u.q = *(const uint4*)(src + row * 64 + c);
#pragma unroll
    for (int j = 0; j < 8; ++j) t[row][c + j] = u.s[j];
  }
  __syncthreads();
  unsigned short* dst = out + (long)bh * 64 * VT_STRIDE + lt * 64;
#pragma unroll
  for (int p = 0; p < 2; ++p) {
    int idx = tid + p * 256;
    int dv = idx >> 3, lc = (idx & 7) * 8;
    union { uint4 q; unsigned short s[8]; } u;
#pragma unroll
    for (int j = 0; j < 8; ++j) u.s[j] = t[lc + j][dv];
    *(uint4*)(dst + (long)dv * VT_STRIDE + lc) = u.q;
  }
}

// ---------- causal flash attention: 32x32 swapped MFMA + K reg-prefetch ----------
// 1 wave/block, 32 q-rows per wave. Lane (h=lane>>5, c=lane&31) owns q-row q0+c.
// S^T via mfma_32x32x16(A=K,B=Q): reg r -> kv-local (r&3)+8*(r>>2)+4h, col=c.
DEV void attn_tile(int T, int nt, int qabs, int h, int c,
                   const unsigned short* __restrict__ kbase,
                   const unsigned short* __restrict__ vbase,
                   const short8 (&qf)[4],
                   const short8 (&kc0)[4], const short8 (&kc1)[4],
                   short8 (&kn0)[4], short8 (&kn1)[4],
                   floatx16& ctx0, floatx16& ctx1, float& m_, float& l_) {
  // prefetch K(T+1) into the other buffer (clamped on last tile; result unused)
  {
    const int Tn = T + 1 < nt ? T + 1 : T;
    const unsigned short* kpn = kbase + (long)Tn * 4096;
#pragma unroll
    for (int d = 0; d < 4; ++d) kn0[d] = *(const short8*)(kpn + d * 16);
#pragma unroll
    for (int d = 0; d < 4; ++d) kn1[d] = *(const short8*)(kpn + 32 * 64 + d * 16);
  }
  // V^T fragments for this tile (consumed after softmax -> latency hidden)
  const unsigned short* vp = vbase + T * 64;
  short8 vf0[4], vf1[4];
#pragma unroll
  for (int m = 0; m < 4; ++m) vf0[m] = *(const short8*)(vp + m * 16);
#pragma unroll
  for (int m = 0; m < 4; ++m) vf1[m] = *(const short8*)(vp + 32 * VT_STRIDE + m * 16);

  // S^T tiles from current (already-resident) K fragments
  floatx16 s0 = {}, s1 = {};
#pragma unroll
  for (int d = 0; d < 4; ++d)
    s0 = __builtin_amdgcn_mfma_f32_32x32x16_bf16(kc0[d], qf[d], s0, 0, 0, 0);
#pragma unroll
  for (int d = 0; d < 4; ++d)
    s1 = __builtin_amdgcn_mfma_f32_32x32x16_bf16(kc1[d], qf[d], s1, 0, 0, 0);

  // causal mask (uniform branch, last tile only)
  if (T == nt - 1) {
    const int kvb = T * 64 + 4 * h;
#pragma unroll
    for (int r = 0; r < 16; ++r) {
      const int off = (r & 3) + 8 * (r >> 2);
      if (kvb + off > qabs) s0[r] = -1e30f;
      if (kvb + 32 + off > qabs) s1[r] = -1e30f;
    }
  }
  // softmax (scalar per lane): depth-5 trees + 2 cross-lane ops
  float a4[8];
#pragma unroll
  for (int j = 0; j < 4; ++j) {
    a4[j]     = fmaxf(fmaxf(s0[4 * j], s0[4 * j + 1]), fmaxf(s0[4 * j + 2], s0[4 * j + 3]));
    a4[4 + j] = fmaxf(fmaxf(s1[4 * j], s1[4 * j + 1]), fmaxf(s1[4 * j + 2], s1[4 * j + 3]));
  }
  float mx = fmaxf(fmaxf(fmaxf(a4[0], a4[1]), fmaxf(a4[2], a4[3])),
                   fmaxf(fmaxf(a4[4], a4[5]), fmaxf(a4[6], a4[7])));
  mx = fmaxf(mx, __shfl_xor(mx, 32));
  float mn = fmaxf(m_, mx);
  float sc = exp2f(m_ - mn);
  m_ = mn;
#pragma unroll
  for (int r = 0; r < 16; ++r) s0[r] = exp2f(s0[r] - m_);
#pragma unroll
  for (int r = 0; r < 16; ++r) s1[r] = exp2f(s1[r] - m_);
  float b4[8];
#pragma unroll
  for (int j = 0; j < 4; ++j) {
    b4[j]     = (s0[4 * j] + s0[4 * j + 1]) + (s0[4 * j + 2] + s0[4 * j + 3]);
    b4[4 + j] = (s1[4 * j] + s1[4 * j + 1]) + (s1[4 * j + 2] + s1[4 * j + 3]);
  }
  float rs = ((b4[0] + b4[1]) + (b4[2] + b4[3])) + ((b4[4] + b4[5]) + (b4[6] + b4[7]));
  rs += __shfl_xor(rs, 32);
  l_ = l_ * sc + rs;
#pragma unroll
  for (int r = 0; r < 16; ++r) { ctx0[r] *= sc; ctx1[r] *= sc; }

  // pack P to bf16 dwords
  uint32_t pd0[8], pd1[8];
#pragma unroll
  for (int d = 0; d < 8; ++d) {
    pd0[d] = cvtpk(s0[2 * d], s0[2 * d + 1]);
    pd1[d] = cvtpk(s1[2 * d], s1[2 * d + 1]);
  }
  // PV: per kvs-subtile, per kseg: B-frag via 2 shfl_xor(32) + selects
#pragma unroll
  for (int kvs = 0; kvs < 2; ++kvs) {
    const uint32_t* pd = kvs ? pd1 : pd0;
#pragma unroll
    for (int ks = 0; ks < 2; ++ks) {
      uint32_t sel0 = h ? pd[4 * ks]     : pd[4 * ks + 2];
      uint32_t sel1 = h ? pd[4 * ks + 1] : pd[4 * ks + 3];
      uint32_t r0 = __shfl_xor(sel0, 32);
      uint32_t r1 = __shfl_xor(sel1, 32);
      union { uint32_t u[4]; short8 s; } bu;
      bu.u[0] = h ? r0 : pd[4 * ks];
      bu.u[1] = h ? r1 : pd[4 * ks + 1];
      bu.u[2] = h ? pd[4 * ks + 2] : r0;
      bu.u[3] = h ? pd[4 * ks + 3] : r1;
      ctx0 = __builtin_amdgcn_mfma_f32_32x32x16_bf16(vf0[kvs * 2 + ks], bu.s, ctx0, 0, 0, 0);
      ctx1 = __builtin_amdgcn_mfma_f32_32x32x16_bf16(vf1[kvs * 2 + ks], bu.s, ctx1, 0, 0, 0);
    }
  }
}

__global__ __launch_bounds__(64) void k_attn(
    const unsigned short* __restrict__ Q, const unsigned short* __restrict__ K,
    const unsigned short* __restrict__ Vt, unsigned short* __restrict__ O) {
  const int bid = blockIdx.x;              // 2048 blocks = 8 XCD * 256
  const int xcd = bid & 7, idx = bid >> 3;
  const int head = idx >> 6;               // 4 heads per XCD -> K/V L2-resident
  const int a = idx & 63;
  // SIMD-balance: the two waves co-resident on a SIMD carry heads h and h+2
  // with the SAME a (RR placement) -> give them complementary q-subtiles.
  const int qs = (head < 2) ? a : 63 - a;
  const int bh = xcd * 4 + head;
  const int lane = threadIdx.x & 63;
  const int h = lane >> 5, c = lane & 31;
  const long hoff = (long)bh * 2048 * 64;
  const unsigned short* Qh = Q + hoff;
  const unsigned short* Kh = K + hoff;
  const unsigned short* Vh = Vt + (long)bh * 64 * VT_STRIDE;
  const int q0 = qs * 32, qabs = q0 + c;
  const int nt = (qs >> 1) + 1;
  const unsigned short* kbase = Kh + (long)c * 64 + 8 * h;
  const unsigned short* vbase = Vh + (long)c * VT_STRIDE + 8 * h;

  // Q fragment (B-operand), hoisted: qf[dseg] = Q[q0+c][dseg*16+8h+j]
  short8 qf[4];
#pragma unroll
  for (int d = 0; d < 4; ++d)
    qf[d] = *(const short8*)(Qh + (long)(q0 + c) * 64 + d * 16 + 8 * h);

  floatx16 ctx0 = {}, ctx1 = {};  // ctx^T[dv][q]
  float m_ = -1e30f, l_ = 0.f;

  // prologue: K(0) into buffer A
  short8 kA0[4], kA1[4], kB0[4], kB1[4];
#pragma unroll
  for (int d = 0; d < 4; ++d) kA0[d] = *(const short8*)(kbase + d * 16);
#pragma unroll
  for (int d = 0; d < 4; ++d) kA1[d] = *(const short8*)(kbase + 32 * 64 + d * 16);

  int T = 0;
  while (true) {
    attn_tile(T, nt, qabs, h, c, kbase, vbase, qf, kA0, kA1, kB0, kB1, ctx0, ctx1, m_, l_);
    if (++T >= nt) break;
    attn_tile(T, nt, qabs, h, c, kbase, vbase, qf, kB0, kB1, kA0, kA1, ctx0, ctx1, m_, l_);
    if (++T >= nt) break;
  }
  // epilogue: lane owns q-row q0+c; dv = dvs*32 + 8m + 4h + (0..3)
  const int b = bh >> 4, hd = bh & 15;
  float inv = 1.f / l_;
  unsigned short* orow = O + (long)(b * 2048 + q0 + c) * 1024 + hd * 64;
#pragma unroll
  for (int m = 0; m < 4; ++m) {
    uint2 w0, w1;
    w0.x = cvtpk(ctx0[4 * m] * inv, ctx0[4 * m + 1] * inv);
    w0.y = cvtpk(ctx0[4 * m + 2] * inv, ctx0[4 * m + 3] * inv);
    *(uint2*)(orow + 8 * m + 4 * h) = w0;
    w1.x = cvtpk(ctx1[4 * m] * inv, ctx1[4 * m + 1] * inv);
    w1.y = cvtpk(ctx1[4 * m + 2] * inv, ctx1[4 * m + 3] * inv);
    *(uint2*)(orow + 32 + 8 * m + 4 * h) = w1;
  }
}

extern "C" void kernel_launch(void* const* d_in, const int* in_sizes, int n_in,
                              void* d_out, int out_size, void* d_ws, size_t ws_size,
                              hipStream_t stream) {
  const float* X  = (const float*)d_in[0];
  const float* Wq = (const float*)d_in[1];
  const float* Wk = (const float*)d_in[2];
  const float* Wv = (const float*)d_in[3];
  const float* Wo = (const float*)d_in[4];
  unsigned short* Xb  = (unsigned short*)d_ws;   // 4M elems bf16 X
  unsigned short* Wqb = Xb + (4l << 20);
  unsigned short* Wkb = Xb + (5l << 20);
  unsigned short* Wvb = Xb + (6l << 20);
  unsigned short* Wob = Xb + (7l << 20);
  unsigned short* Qw  = Xb + (8l << 20);         // [2,16,2048,64]
  unsigned short* Kw  = Xb + (12l << 20);
  unsigned short* Vw  = Xb + (16l << 20);
  unsigned short* Vtw = Xb;  // V^T [32][64][2080]: aliases X/Wq/Wk/Wv (dead after QKV GEMM)
  unsigned short* Cw  = Xb + (20l << 20);        // ctx [b,l,1024]
  float* Out = (float*)d_out;

  k_convert<<<4096, 256, 0, stream>>>(X, Wq, Wk, Wv, Wo, Xb);
  k_gemm<0><<<dim3(32, 24), 256, 0, stream>>>(Xb, Wqb, Wkb, Wvb, Qw, Kw, Vw, nullptr, 1024);
  k_rope<<<1024, 256, 0, stream>>>(Qw, 0.18033688011112042f);  // log2(e)/8
  k_transpose<<<1024, 256, 0, stream>>>(Vw, Vtw);
  k_attn<<<2048, 64, 0, stream>>>(Qw, Kw, Vtw, Cw);
  k_gemm<1><<<dim3(32, 8), 256, 0, stream>>>(Cw, Wob, nullptr, nullptr,
                                             nullptr, nullptr, nullptr, Out, 1024);
}